// Round 3
// baseline (801.053 us; speedup 1.0000x reference)
//
#include <hip/hip_runtime.h>
#include <math.h>

#define IN_CAPS 512
#define QN      512
#define IN_DIM  768
#define NCAPS   64
#define DCAPS   16
#define CD      1024   // NCAPS*DCAPS

__device__ __forceinline__ float tanh_fast(float x){
  float e = __expf(2.0f*x);
  return 1.0f - 2.0f/(e+1.0f);
}

template<int CTRL>
__device__ __forceinline__ float dpp_add(float v){
  int r = __builtin_amdgcn_update_dpp(0, __float_as_int(v), CTRL, 0xF, 0xF, true);
  return v + __int_as_float(r);
}

// sum across 64 lanes: 4 DPP adds (VALU) + 2 cross-row shuffles
__device__ __forceinline__ float wave_sum64(float v){
  v = dpp_add<0xB1>(v);    // quad_perm [1,0,3,2]  (xor 1)
  v = dpp_add<0x4E>(v);    // quad_perm [2,3,0,1]  (xor 2)
  v = dpp_add<0x141>(v);   // row_half_mirror      (xor-4 equivalent)
  v = dpp_add<0x140>(v);   // row_mirror           (xor-8 equivalent)
  v += __shfl_xor(v, 16, 64);
  v += __shfl_xor(v, 32, 64);
  return v;
}

#define LD16(dst, ptr) { const float4* _p=(const float4*)(ptr); \
  float4 _a=_p[0], _b=_p[1], _c=_p[2], _d=_p[3]; \
  dst[0]=_a.x; dst[1]=_a.y; dst[2]=_a.z; dst[3]=_a.w; \
  dst[4]=_b.x; dst[5]=_b.y; dst[6]=_b.z; dst[7]=_b.w; \
  dst[8]=_c.x; dst[9]=_c.y; dst[10]=_c.z; dst[11]=_c.w; \
  dst[12]=_d.x; dst[13]=_d.y; dst[14]=_d.z; dst[15]=_d.w; }

// ---------------- K0: hat = [m;q] @ W_w + W_b  (1024x768 @ 768x1024) ----------------
__global__ __launch_bounds__(256) void gemm_hat(const float* __restrict__ m,
                                                const float* __restrict__ q,
                                                const float* __restrict__ Ww,
                                                const float* __restrict__ Wb,
                                                float* __restrict__ hat)
{
  __shared__ float As[16][65];   // [k][row]  (A transposed)
  __shared__ float Bs[16][65];   // [k][col]
  const int tid = threadIdx.x;
  const int bm = blockIdx.y, bn = blockIdx.x;
  const int tx = tid & 15, ty = tid >> 4;

  float acc[4][4];
  #pragma unroll
  for (int a=0;a<4;a++)
    #pragma unroll
    for (int b=0;b<4;b++) acc[a][b]=0.0f;

  const int r  = tid >> 2;            // 0..63 (row within tile)
  const int kk = (tid & 3) << 2;      // 0,4,8,12
  const int row = bm*64 + r;
  const float* srcA = (row < IN_CAPS) ? (m + row*IN_DIM) : (q + (row-IN_CAPS)*IN_DIM);
  const int krow = tid >> 4;          // 0..15
  const int cc   = (tid & 15) << 2;   // 0..60

  for (int k0=0; k0<IN_DIM; k0+=16){
    float4 av = *(const float4*)(srcA + k0 + kk);
    As[kk+0][r]=av.x; As[kk+1][r]=av.y; As[kk+2][r]=av.z; As[kk+3][r]=av.w;
    float4 bv = *(const float4*)(Ww + (size_t)(k0+krow)*CD + bn*64 + cc);
    Bs[krow][cc+0]=bv.x; Bs[krow][cc+1]=bv.y; Bs[krow][cc+2]=bv.z; Bs[krow][cc+3]=bv.w;
    __syncthreads();
    #pragma unroll
    for (int k=0;k<16;k++){
      float a[4], b[4];
      #pragma unroll
      for (int j=0;j<4;j++) a[j] = As[k][ty*4+j];
      #pragma unroll
      for (int j=0;j<4;j++) b[j] = Bs[k][tx*4+j];
      #pragma unroll
      for (int ii=0;ii<4;ii++)
        #pragma unroll
        for (int jj=0;jj<4;jj++) acc[ii][jj] += a[ii]*b[jj];
    }
    __syncthreads();
  }
  #pragma unroll
  for (int ii=0;ii<4;ii++){
    const int orow = bm*64 + ty*4 + ii;
    #pragma unroll
    for (int jj=0;jj<4;jj++){
      const int ocol = bn*64 + tx*4 + jj;
      hat[(size_t)orow*CD + ocol] = acc[ii][jj] + Wb[ocol];
    }
  }
}

// ---------------- K1: per-(i,c) stats:  rnm = rsqrt(||m-mean||^2),  sm = sum_d m ----------------
__global__ __launch_bounds__(256) void stats_kernel(const float* __restrict__ hat,
                                                    float* __restrict__ rnm,
                                                    float* __restrict__ sm)
{
  const int t = blockIdx.x*256 + threadIdx.x;    // 0..32767
  const int i = t >> 6, c = t & 63;
  float v[16];
  LD16(v, hat + (size_t)i*CD + c*16);
  float s=0.f;
  #pragma unroll
  for (int d=0;d<16;d++) s += v[d];
  const float mean = s*(1.0f/16.0f);
  float n2=0.f;
  #pragma unroll
  for (int d=0;d<16;d++){ float x=v[d]-mean; n2+=x*x; }
  rnm[t] = __frsqrt_rn(n2 + 1e-12f);
  sm[t]  = s;
}

// two-stage cross-wave reduction of acc[16] (per (c,d)) into hvl, 16 waves
#define BLOCK_REDUCE() do { \
  if (w >= 8){ _Pragma("unroll") for (int d=0;d<16;d++) tmp[w-8][c][d] = acc[d]; } \
  __syncthreads(); \
  if (w < 8){ _Pragma("unroll") for (int d=0;d<16;d++){ acc[d] += tmp[w][c][d]; tmp[w][c][d] = acc[d]; } } \
  __syncthreads(); \
  { const int cc = tid >> 4, dd = tid & 15; \
    float s = tmp[0][cc][dd]+tmp[1][cc][dd]+tmp[2][cc][dd]+tmp[3][cc][dd] \
            + tmp[4][cc][dd]+tmp[5][cc][dd]+tmp[6][cc][dd]+tmp[7][cc][dd]; \
    hvl[cc][dd] = s; } \
  __syncthreads(); \
} while(0)

// ---------------- K2: routing, one q per block, 16 waves ----------------
__global__ __launch_bounds__(1024, 8) void routing_kernel(const float* __restrict__ hat,
                                                          const float* __restrict__ rnm_g,
                                                          const float* __restrict__ sm_g,
                                                          float* __restrict__ out)
{
  __shared__ float tmp[8][64][17];   // 34.8 KB
  __shared__ float hvl[64][17];      //  4.4 KB
  const int qidx = blockIdx.x;
  const int tid = threadIdx.x;
  const int w = tid >> 6;       // wave 0..15
  const int c = tid & 63;       // lane = capsule

  // q_cur (= hat_q row), per lane c holds the 16-dim capsule vector
  float qc[16];
  LD16(qc, hat + (size_t)(IN_CAPS + qidx)*CD + c*16);

  float qcc1[16];
  float s1, s2, s3;             // rsqrt(nq2_x)
  {
    float s=0.f;
    #pragma unroll
    for (int d=0;d<16;d++) s += qc[d];
    const float mean = s*(1.0f/16.0f);
    float n2=0.f;
    #pragma unroll
    for (int d=0;d<16;d++){ qcc1[d]=qc[d]-mean; n2 += qcc1[d]*qcc1[d]; }
    s1 = __frsqrt_rn(n2 + 1e-12f);
  }

  float v1[16], v2[16], acc[16];
  const int i0 = w*32, i1 = i0+32;

  // ======== pass 1:  hat_v1 = sum_i (1/64 + p1) * m ========
  #pragma unroll
  for (int d=0;d<16;d++) acc[d]=0.f;
  for (int i=i0;i<i1;i++){
    float mr[16];
    LD16(mr, hat + (size_t)i*CD + c*16);
    const float rnm = rnm_g[i*64 + c];
    float n1=0.f;
    #pragma unroll
    for (int d=0;d<16;d++) n1 += mr[d]*qcc1[d];
    const float p1 = tanh_fast(n1*rnm*s1);
    const float wgt = 0.015625f + p1;   // softmax(0) = 1/64 exactly
    #pragma unroll
    for (int d=0;d<16;d++) acc[d] += wgt*mr[d];
  }
  BLOCK_REDUCE();
  {
    float n2=0.f;
    #pragma unroll
    for (int d=0;d<16;d++){ v1[d]=hvl[c][d]; n2 += v1[d]*v1[d]; }
    const float sc = n2 / ((1.0f+n2)*sqrtf(n2+1e-8f));
    #pragma unroll
    for (int d=0;d<16;d++) v1[d] *= sc;
  }
  // q_cur2 = (q_cur1 + v1)/2 ; nq2_2 via sum/sumsq; mv1 = mean(v1)
  float mv1, mv2;
  {
    float sv=0.f;
    #pragma unroll
    for (int d=0;d<16;d++) sv += v1[d];
    mv1 = sv*(1.0f/16.0f);
    float s=0.f, ss=0.f;
    #pragma unroll
    for (int d=0;d<16;d++){ qc[d] = 0.5f*(qc[d]+v1[d]); s += qc[d]; ss += qc[d]*qc[d]; }
    const float mean = s*(1.0f/16.0f);
    const float n2 = ss - 16.0f*mean*mean;
    s2 = __frsqrt_rn(n2 + 1e-12f);
  }

  // ======== pass 2:  hat_v2 = sum_i (softmax_c(p1*cv1) + p2) * m ========
  #pragma unroll
  for (int d=0;d<16;d++) acc[d]=0.f;
  for (int i=i0;i<i1;i++){
    float mr[16];
    LD16(mr, hat + (size_t)i*CD + c*16);
    const float rnm = rnm_g[i*64 + c];
    const float smi = sm_g[i*64 + c];
    float n1=0.f, cv1=0.f;
    #pragma unroll
    for (int d=0;d<16;d++){ n1 += mr[d]*qcc1[d]; cv1 += mr[d]*v1[d]; }
    const float p1 = tanh_fast(n1*rnm*s1);
    const float n2d = 0.5f*(n1 + cv1 - mv1*smi);
    const float p2 = tanh_fast(n2d*rnm*s2);
    const float e  = __expf(p1*cv1);             // logits bounded, no max needed
    const float ssum = wave_sum64(e);
    const float wgt = e*__frcp_rn(ssum) + p2;
    #pragma unroll
    for (int d=0;d<16;d++) acc[d] += wgt*mr[d];
  }
  BLOCK_REDUCE();
  {
    float n2=0.f;
    #pragma unroll
    for (int d=0;d<16;d++){ v2[d]=hvl[c][d]; n2 += v2[d]*v2[d]; }
    const float sc = n2 / ((1.0f+n2)*sqrtf(n2+1e-8f));
    #pragma unroll
    for (int d=0;d<16;d++) v2[d] *= sc;
  }
  // q_cur3 = (q_cur2 + v2)/2 ; nq2_3 ; mv2 = mean(v2)
  {
    float sv=0.f;
    #pragma unroll
    for (int d=0;d<16;d++) sv += v2[d];
    mv2 = sv*(1.0f/16.0f);
    float s=0.f, ss=0.f;
    #pragma unroll
    for (int d=0;d<16;d++){ qc[d] = 0.5f*(qc[d]+v2[d]); s += qc[d]; ss += qc[d]*qc[d]; }
    const float mean = s*(1.0f/16.0f);
    const float n2 = ss - 16.0f*mean*mean;
    s3 = __frsqrt_rn(n2 + 1e-12f);
  }

  // ======== pass 3:  out = squash( sum_i (softmax_c(p1*cv1+p2*cv2) + p3) * m ) ========
  #pragma unroll
  for (int d=0;d<16;d++) acc[d]=0.f;
  for (int i=i0;i<i1;i++){
    float mr[16];
    LD16(mr, hat + (size_t)i*CD + c*16);
    const float rnm = rnm_g[i*64 + c];
    const float smi = sm_g[i*64 + c];
    float n1=0.f, cv1=0.f, cv2=0.f;
    #pragma unroll
    for (int d=0;d<16;d++){
      n1  += mr[d]*qcc1[d];
      cv1 += mr[d]*v1[d];
      cv2 += mr[d]*v2[d];
    }
    const float p1 = tanh_fast(n1*rnm*s1);
    const float n2d = 0.5f*(n1 + cv1 - mv1*smi);
    const float p2 = tanh_fast(n2d*rnm*s2);
    const float n3 = 0.5f*(n2d + cv2 - mv2*smi);
    const float p3 = tanh_fast(n3*rnm*s3);
    const float e  = __expf(p1*cv1 + p2*cv2);
    const float ssum = wave_sum64(e);
    const float wgt = e*__frcp_rn(ssum) + p3;
    #pragma unroll
    for (int d=0;d<16;d++) acc[d] += wgt*mr[d];
  }
  BLOCK_REDUCE();
  if (w==0){
    float hv[16]; float n2=0.f;
    #pragma unroll
    for (int d=0;d<16;d++){ hv[d]=hvl[c][d]; n2 += hv[d]*hv[d]; }
    const float sc = n2 / ((1.0f+n2)*sqrtf(n2+1e-8f));
    float4* op = (float4*)(out + (size_t)qidx*CD + c*16);
    float o[16];
    #pragma unroll
    for (int d=0;d<16;d++) o[d] = hv[d]*sc;
    op[0] = make_float4(o[0],o[1],o[2],o[3]);
    op[1] = make_float4(o[4],o[5],o[6],o[7]);
    op[2] = make_float4(o[8],o[9],o[10],o[11]);
    op[3] = make_float4(o[12],o[13],o[14],o[15]);
  }
}

extern "C" void kernel_launch(void* const* d_in, const int* in_sizes, int n_in,
                              void* d_out, int out_size, void* d_ws, size_t ws_size,
                              hipStream_t stream)
{
  const float* m  = (const float*)d_in[0];
  const float* q  = (const float*)d_in[1];
  const float* Ww = (const float*)d_in[2];
  const float* Wb = (const float*)d_in[3];
  float* out = (float*)d_out;

  float* hat  = (float*)d_ws;                 // 1024*1024 floats (rows 0..511 = hat_m, 512..1023 = hat_q)
  float* rnm  = hat + (size_t)1024*1024;      // 512*64
  float* sm   = rnm + (size_t)512*64;         // 512*64

  dim3 g0(16,16);
  gemm_hat<<<g0, 256, 0, stream>>>(m, q, Ww, Wb, hat);
  stats_kernel<<<128, 256, 0, stream>>>(hat, rnm, sm);
  routing_kernel<<<512, 1024, 0, stream>>>(hat, rnm, sm, out);
}

// Round 4
// 758.841 us; speedup vs baseline: 1.0556x; 1.0556x over previous
//
#include <hip/hip_runtime.h>
#include <math.h>

#define IN_CAPS 512
#define QN      512
#define IN_DIM  768
#define NCAPS   64
#define DCAPS   16
#define CD      1024   // NCAPS*DCAPS

__device__ __forceinline__ float tanh_fast(float x){
  float e = __expf(2.0f*x);
  return 1.0f - 2.0f/(e+1.0f);
}

template<int CTRL>
__device__ __forceinline__ float dpp_add(float v){
  int r = __builtin_amdgcn_update_dpp(0, __float_as_int(v), CTRL, 0xF, 0xF, true);
  return v + __int_as_float(r);
}

// sum across 64 lanes: 4 DPP VALU adds + 1 ds_swizzle (xor16) + 1 shfl (xor32)
__device__ __forceinline__ float wave_sum64(float v){
  v = dpp_add<0xB1>(v);    // quad_perm xor1
  v = dpp_add<0x4E>(v);    // quad_perm xor2
  v = dpp_add<0x141>(v);   // row_half_mirror (xor4-equivalent after prior steps)
  v = dpp_add<0x140>(v);   // row_mirror      (xor8-equivalent)
  { int r = __builtin_amdgcn_ds_swizzle(__float_as_int(v), 0x401F);  // xor16 within 32
    v += __int_as_float(r); }
  v += __shfl_xor(v, 32, 64);
  return v;
}

#define LD16(dst, ptr) { const float4* _p=(const float4*)(ptr); \
  float4 _a=_p[0], _b=_p[1], _c=_p[2], _d=_p[3]; \
  dst[0]=_a.x; dst[1]=_a.y; dst[2]=_a.z; dst[3]=_a.w; \
  dst[4]=_b.x; dst[5]=_b.y; dst[6]=_b.z; dst[7]=_b.w; \
  dst[8]=_c.x; dst[9]=_c.y; dst[10]=_c.z; dst[11]=_c.w; \
  dst[12]=_d.x; dst[13]=_d.y; dst[14]=_d.z; dst[15]=_d.w; }

// ---------------- K0: hat = [m;q] @ W_w + W_b  (1024x768 @ 768x1024) ----------------
__global__ __launch_bounds__(256) void gemm_hat(const float* __restrict__ m,
                                                const float* __restrict__ q,
                                                const float* __restrict__ Ww,
                                                const float* __restrict__ Wb,
                                                float* __restrict__ hat)
{
  __shared__ float As[16][65];   // [k][row]  (A transposed)
  __shared__ float Bs[16][65];   // [k][col]
  const int tid = threadIdx.x;
  const int bm = blockIdx.y, bn = blockIdx.x;
  const int tx = tid & 15, ty = tid >> 4;

  float acc[4][4];
  #pragma unroll
  for (int a=0;a<4;a++)
    #pragma unroll
    for (int b=0;b<4;b++) acc[a][b]=0.0f;

  const int r  = tid >> 2;            // 0..63 (row within tile)
  const int kk = (tid & 3) << 2;      // 0,4,8,12
  const int row = bm*64 + r;
  const float* srcA = (row < IN_CAPS) ? (m + row*IN_DIM) : (q + (row-IN_CAPS)*IN_DIM);
  const int krow = tid >> 4;          // 0..15
  const int cc   = (tid & 15) << 2;   // 0..60

  for (int k0=0; k0<IN_DIM; k0+=16){
    float4 av = *(const float4*)(srcA + k0 + kk);
    As[kk+0][r]=av.x; As[kk+1][r]=av.y; As[kk+2][r]=av.z; As[kk+3][r]=av.w;
    float4 bv = *(const float4*)(Ww + (size_t)(k0+krow)*CD + bn*64 + cc);
    Bs[krow][cc+0]=bv.x; Bs[krow][cc+1]=bv.y; Bs[krow][cc+2]=bv.z; Bs[krow][cc+3]=bv.w;
    __syncthreads();
    #pragma unroll
    for (int k=0;k<16;k++){
      float a[4], b[4];
      #pragma unroll
      for (int j=0;j<4;j++) a[j] = As[k][ty*4+j];
      #pragma unroll
      for (int j=0;j<4;j++) b[j] = Bs[k][tx*4+j];
      #pragma unroll
      for (int ii=0;ii<4;ii++)
        #pragma unroll
        for (int jj=0;jj<4;jj++) acc[ii][jj] += a[ii]*b[jj];
    }
    __syncthreads();
  }
  #pragma unroll
  for (int ii=0;ii<4;ii++){
    const int orow = bm*64 + ty*4 + ii;
    #pragma unroll
    for (int jj=0;jj<4;jj++){
      const int ocol = bn*64 + tx*4 + jj;
      hat[(size_t)orow*CD + ocol] = acc[ii][jj] + Wb[ocol];
    }
  }
}

// ---------------- K1: per-(i,c) stats:  rs = (rsqrt(||m-mean||^2), sum_d m) ----------------
__global__ __launch_bounds__(256) void stats_kernel(const float* __restrict__ hat,
                                                    float2* __restrict__ rs)
{
  const int t = blockIdx.x*256 + threadIdx.x;    // 0..32767
  const int i = t >> 6, c = t & 63;
  float v[16];
  LD16(v, hat + (size_t)i*CD + c*16);
  float s=0.f;
  #pragma unroll
  for (int d=0;d<16;d++) s += v[d];
  const float mean = s*(1.0f/16.0f);
  float n2=0.f;
  #pragma unroll
  for (int d=0;d<16;d++){ float x=v[d]-mean; n2+=x*x; }
  rs[t] = make_float2(__frsqrt_rn(n2 + 1e-12f), s);
}

// cross-wave reduction of acc[16] into hvl, 8 waves, 4-slot tmp
#define BLOCK_REDUCE() do { \
  if (w >= 4){ _Pragma("unroll") for (int d=0;d<16;d++) tmp[w-4][c][d] = acc[d]; } \
  __syncthreads(); \
  if (w < 4){ _Pragma("unroll") for (int d=0;d<16;d++){ acc[d] += tmp[w][c][d]; tmp[w][c][d] = acc[d]; } } \
  __syncthreads(); \
  { const int cc0 = tid >> 4, dd0 = tid & 15; \
    hvl[cc0][dd0] = tmp[0][cc0][dd0]+tmp[1][cc0][dd0]+tmp[2][cc0][dd0]+tmp[3][cc0][dd0]; \
    const int e1 = tid + 512, cc1 = e1 >> 4, dd1 = e1 & 15; \
    hvl[cc1][dd1] = tmp[0][cc1][dd1]+tmp[1][cc1][dd1]+tmp[2][cc1][dd1]+tmp[3][cc1][dd1]; } \
  __syncthreads(); \
} while(0)

// ---------------- K2: routing, one q per block, 8 waves ----------------
__global__ __launch_bounds__(512, 6) void routing_kernel(const float* __restrict__ hat,
                                                         const float2* __restrict__ rs_g,
                                                         float* __restrict__ out)
{
  __shared__ float tmp[4][64][17];   // 17.4 KB
  __shared__ float hvl[64][17];      //  4.4 KB
  const int qidx = blockIdx.x;
  const int tid = threadIdx.x;
  const int w = tid >> 6;       // wave 0..7
  const int c = tid & 63;       // lane = capsule

  // q_cur (= hat_q row), per lane c holds the 16-dim capsule vector
  float qc[16];
  LD16(qc, hat + (size_t)(IN_CAPS + qidx)*CD + c*16);

  float qcc1[16];
  float s1, s2, s3;             // rsqrt(nq2_x)
  {
    float s=0.f;
    #pragma unroll
    for (int d=0;d<16;d++) s += qc[d];
    const float mean = s*(1.0f/16.0f);
    float n2=0.f;
    #pragma unroll
    for (int d=0;d<16;d++){ qcc1[d]=qc[d]-mean; n2 += qcc1[d]*qcc1[d]; }
    s1 = __frsqrt_rn(n2 + 1e-12f);
  }

  float v1[16], v2[16], acc[16];
  const int i0 = w*64, i1 = i0+64;

  // ======== pass 1:  hat_v1 = sum_i (1/64 + p1) * m ========
  #pragma unroll
  for (int d=0;d<16;d++) acc[d]=0.f;
  {
    const float* mp = hat + (size_t)i0*CD + c*16;
    const float2* rp = rs_g + i0*64 + c;
    for (int i=i0;i<i1;i++, mp+=CD, rp+=64){
      float mr[16];
      LD16(mr, mp);
      const float rnm = rp->x;
      float n1=0.f;
      #pragma unroll
      for (int d=0;d<16;d++) n1 += mr[d]*qcc1[d];
      const float p1 = tanh_fast(n1*rnm*s1);
      const float wgt = 0.015625f + p1;   // softmax(0) = 1/64 exactly
      #pragma unroll
      for (int d=0;d<16;d++) acc[d] += wgt*mr[d];
    }
  }
  BLOCK_REDUCE();
  {
    float n2=0.f;
    #pragma unroll
    for (int d=0;d<16;d++){ v1[d]=hvl[c][d]; n2 += v1[d]*v1[d]; }
    const float sc = n2 / ((1.0f+n2)*sqrtf(n2+1e-8f));
    #pragma unroll
    for (int d=0;d<16;d++) v1[d] *= sc;
  }
  // q_cur2 = (q_cur1 + v1)/2 ; mv1 = mean(v1)
  float mv1, mv2;
  {
    float sv=0.f;
    #pragma unroll
    for (int d=0;d<16;d++) sv += v1[d];
    mv1 = sv*(1.0f/16.0f);
    float s=0.f, ss=0.f;
    #pragma unroll
    for (int d=0;d<16;d++){ qc[d] = 0.5f*(qc[d]+v1[d]); s += qc[d]; ss += qc[d]*qc[d]; }
    const float mean = s*(1.0f/16.0f);
    const float n2 = ss - 16.0f*mean*mean;
    s2 = __frsqrt_rn(n2 + 1e-12f);
  }

  // ======== pass 2:  hat_v2 = sum_i (softmax_c(p1*cv1) + p2) * m ========
  #pragma unroll
  for (int d=0;d<16;d++) acc[d]=0.f;
  {
    const float* mp = hat + (size_t)i0*CD + c*16;
    const float2* rp = rs_g + i0*64 + c;
    for (int i=i0;i<i1;i++, mp+=CD, rp+=64){
      float mr[16];
      LD16(mr, mp);
      const float2 rsv = *rp;
      float n1=0.f, cv1=0.f;
      #pragma unroll
      for (int d=0;d<16;d++){ n1 += mr[d]*qcc1[d]; cv1 += mr[d]*v1[d]; }
      const float p1 = tanh_fast(n1*rsv.x*s1);
      const float n2d = 0.5f*(n1 + cv1 - mv1*rsv.y);
      const float p2 = tanh_fast(n2d*rsv.x*s2);
      const float e  = __expf(p1*cv1);             // logits bounded, no max needed
      const float ssum = wave_sum64(e);
      const float wgt = e*__frcp_rn(ssum) + p2;
      #pragma unroll
      for (int d=0;d<16;d++) acc[d] += wgt*mr[d];
    }
  }
  BLOCK_REDUCE();
  {
    float n2=0.f;
    #pragma unroll
    for (int d=0;d<16;d++){ v2[d]=hvl[c][d]; n2 += v2[d]*v2[d]; }
    const float sc = n2 / ((1.0f+n2)*sqrtf(n2+1e-8f));
    #pragma unroll
    for (int d=0;d<16;d++) v2[d] *= sc;
  }
  // q_cur3 = (q_cur2 + v2)/2 ; mv2 = mean(v2)
  {
    float sv=0.f;
    #pragma unroll
    for (int d=0;d<16;d++) sv += v2[d];
    mv2 = sv*(1.0f/16.0f);
    float s=0.f, ss=0.f;
    #pragma unroll
    for (int d=0;d<16;d++){ qc[d] = 0.5f*(qc[d]+v2[d]); s += qc[d]; ss += qc[d]*qc[d]; }
    const float mean = s*(1.0f/16.0f);
    const float n2 = ss - 16.0f*mean*mean;
    s3 = __frsqrt_rn(n2 + 1e-12f);
  }

  // ======== pass 3:  out = squash( sum_i (softmax_c(p1*cv1+p2*cv2) + p3) * m ) ========
  #pragma unroll
  for (int d=0;d<16;d++) acc[d]=0.f;
  {
    const float* mp = hat + (size_t)i0*CD + c*16;
    const float2* rp = rs_g + i0*64 + c;
    for (int i=i0;i<i1;i++, mp+=CD, rp+=64){
      float mr[16];
      LD16(mr, mp);
      const float2 rsv = *rp;
      float n1=0.f, cv1=0.f, cv2=0.f;
      #pragma unroll
      for (int d=0;d<16;d++){
        n1  += mr[d]*qcc1[d];
        cv1 += mr[d]*v1[d];
        cv2 += mr[d]*v2[d];
      }
      const float p1 = tanh_fast(n1*rsv.x*s1);
      const float n2d = 0.5f*(n1 + cv1 - mv1*rsv.y);
      const float p2 = tanh_fast(n2d*rsv.x*s2);
      const float n3 = 0.5f*(n2d + cv2 - mv2*rsv.y);
      const float p3 = tanh_fast(n3*rsv.x*s3);
      const float e  = __expf(p1*cv1 + p2*cv2);
      const float ssum = wave_sum64(e);
      const float wgt = e*__frcp_rn(ssum) + p3;
      #pragma unroll
      for (int d=0;d<16;d++) acc[d] += wgt*mr[d];
    }
  }
  BLOCK_REDUCE();
  if (w==0){
    float hv[16]; float n2=0.f;
    #pragma unroll
    for (int d=0;d<16;d++){ hv[d]=hvl[c][d]; n2 += hv[d]*hv[d]; }
    const float sc = n2 / ((1.0f+n2)*sqrtf(n2+1e-8f));
    float4* op = (float4*)(out + (size_t)qidx*CD + c*16);
    float o[16];
    #pragma unroll
    for (int d=0;d<16;d++) o[d] = hv[d]*sc;
    op[0] = make_float4(o[0],o[1],o[2],o[3]);
    op[1] = make_float4(o[4],o[5],o[6],o[7]);
    op[2] = make_float4(o[8],o[9],o[10],o[11]);
    op[3] = make_float4(o[12],o[13],o[14],o[15]);
  }
}

extern "C" void kernel_launch(void* const* d_in, const int* in_sizes, int n_in,
                              void* d_out, int out_size, void* d_ws, size_t ws_size,
                              hipStream_t stream)
{
  const float* m  = (const float*)d_in[0];
  const float* q  = (const float*)d_in[1];
  const float* Ww = (const float*)d_in[2];
  const float* Wb = (const float*)d_in[3];
  float* out = (float*)d_out;

  float* hat  = (float*)d_ws;                 // 1024*1024 floats (rows 0..511 = hat_m, 512..1023 = hat_q)
  float2* rs  = (float2*)(hat + (size_t)1024*1024);   // 512*64 float2

  dim3 g0(16,16);
  gemm_hat<<<g0, 256, 0, stream>>>(m, q, Ww, Wb, hat);
  stats_kernel<<<128, 256, 0, stream>>>(hat, rs);
  routing_kernel<<<512, 512, 0, stream>>>(hat, rs, out);
}

// Round 5
// 267.733 us; speedup vs baseline: 2.9920x; 2.8343x over previous
//
#include <hip/hip_runtime.h>
#include <math.h>

#define IN_CAPS 512
#define QN      512
#define IN_DIM  768
#define NCAPS   64
#define DCAPS   16
#define CD      1024   // NCAPS*DCAPS

__device__ __forceinline__ float tanh_fast(float x){
  float e = __expf(2.0f*x);
  return 1.0f - 2.0f/(e+1.0f);
}

template<int CTRL>
__device__ __forceinline__ float dpp_add(float v){
  int r = __builtin_amdgcn_update_dpp(0, __float_as_int(v), CTRL, 0xF, 0xF, true);
  return v + __int_as_float(r);
}

// sum across 64 lanes: 4 DPP VALU adds + 1 ds_swizzle (xor16) + 1 shfl (xor32)
__device__ __forceinline__ float wave_sum64(float v){
  v = dpp_add<0xB1>(v);    // quad_perm xor1
  v = dpp_add<0x4E>(v);    // quad_perm xor2
  v = dpp_add<0x141>(v);   // row_half_mirror
  v = dpp_add<0x140>(v);   // row_mirror
  { int r = __builtin_amdgcn_ds_swizzle(__float_as_int(v), 0x401F);  // xor16 within 32
    v += __int_as_float(r); }
  v += __shfl_xor(v, 32, 64);
  return v;
}

#define LD16(dst, ptr) { const float4* _p=(const float4*)(ptr); \
  float4 _a=_p[0], _b=_p[1], _c=_p[2], _d=_p[3]; \
  dst[0]=_a.x; dst[1]=_a.y; dst[2]=_a.z; dst[3]=_a.w; \
  dst[4]=_b.x; dst[5]=_b.y; dst[6]=_b.z; dst[7]=_b.w; \
  dst[8]=_c.x; dst[9]=_c.y; dst[10]=_c.z; dst[11]=_c.w; \
  dst[12]=_d.x; dst[13]=_d.y; dst[14]=_d.z; dst[15]=_d.w; }

// 2-way-split dot of two 16-vecs (shorter dependence chain)
#define DOT16(res, x, y) { float _e=0.f,_o=0.f; \
  _Pragma("unroll") for (int _d=0;_d<16;_d+=2){ _e += x[_d]*y[_d]; _o += x[_d+1]*y[_d+1]; } \
  res = _e+_o; }

// ---------------- K0: hat = [m;q] @ W_w + W_b  (1024x768 @ 768x1024) ----------------
__global__ __launch_bounds__(256) void gemm_hat(const float* __restrict__ m,
                                                const float* __restrict__ q,
                                                const float* __restrict__ Ww,
                                                const float* __restrict__ Wb,
                                                float* __restrict__ hat)
{
  __shared__ float As[16][65];
  __shared__ float Bs[16][65];
  const int tid = threadIdx.x;
  const int bm = blockIdx.y, bn = blockIdx.x;
  const int tx = tid & 15, ty = tid >> 4;

  float acc[4][4];
  #pragma unroll
  for (int a=0;a<4;a++)
    #pragma unroll
    for (int b=0;b<4;b++) acc[a][b]=0.0f;

  const int r  = tid >> 2;
  const int kk = (tid & 3) << 2;
  const int row = bm*64 + r;
  const float* srcA = (row < IN_CAPS) ? (m + row*IN_DIM) : (q + (row-IN_CAPS)*IN_DIM);
  const int krow = tid >> 4;
  const int cc   = (tid & 15) << 2;

  for (int k0=0; k0<IN_DIM; k0+=16){
    float4 av = *(const float4*)(srcA + k0 + kk);
    As[kk+0][r]=av.x; As[kk+1][r]=av.y; As[kk+2][r]=av.z; As[kk+3][r]=av.w;
    float4 bv = *(const float4*)(Ww + (size_t)(k0+krow)*CD + bn*64 + cc);
    Bs[krow][cc+0]=bv.x; Bs[krow][cc+1]=bv.y; Bs[krow][cc+2]=bv.z; Bs[krow][cc+3]=bv.w;
    __syncthreads();
    #pragma unroll
    for (int k=0;k<16;k++){
      float a[4], b[4];
      #pragma unroll
      for (int j=0;j<4;j++) a[j] = As[k][ty*4+j];
      #pragma unroll
      for (int j=0;j<4;j++) b[j] = Bs[k][tx*4+j];
      #pragma unroll
      for (int ii=0;ii<4;ii++)
        #pragma unroll
        for (int jj=0;jj<4;jj++) acc[ii][jj] += a[ii]*b[jj];
    }
    __syncthreads();
  }
  #pragma unroll
  for (int ii=0;ii<4;ii++){
    const int orow = bm*64 + ty*4 + ii;
    #pragma unroll
    for (int jj=0;jj<4;jj++){
      const int ocol = bn*64 + tx*4 + jj;
      hat[(size_t)orow*CD + ocol] = acc[ii][jj] + Wb[ocol];
    }
  }
}

// ---------------- K1: per-(i,c) stats:  rs = (rsqrt(||m-mean||^2), sum_d m) ----------------
__global__ __launch_bounds__(256) void stats_kernel(const float* __restrict__ hat,
                                                    float2* __restrict__ rs)
{
  const int t = blockIdx.x*256 + threadIdx.x;
  const int i = t >> 6, c = t & 63;
  float v[16];
  LD16(v, hat + (size_t)i*CD + c*16);
  float s=0.f;
  #pragma unroll
  for (int d=0;d<16;d++) s += v[d];
  const float mean = s*(1.0f/16.0f);
  float n2=0.f;
  #pragma unroll
  for (int d=0;d<16;d++){ float x=v[d]-mean; n2+=x*x; }
  rs[t] = make_float2(__frsqrt_rn(n2 + 1e-12f), s);
}

// cross-wave reduction of acc[16] into hvl, 8 waves, 4-slot tmp
#define BLOCK_REDUCE() do { \
  if (w >= 4){ _Pragma("unroll") for (int d=0;d<16;d++) tmp[w-4][c][d] = acc[d]; } \
  __syncthreads(); \
  if (w < 4){ _Pragma("unroll") for (int d=0;d<16;d++){ acc[d] += tmp[w][c][d]; tmp[w][c][d] = acc[d]; } } \
  __syncthreads(); \
  { const int cc0 = tid >> 4, dd0 = tid & 15; \
    hvl[cc0][dd0] = tmp[0][cc0][dd0]+tmp[1][cc0][dd0]+tmp[2][cc0][dd0]+tmp[3][cc0][dd0]; \
    const int e1 = tid + 512, cc1 = e1 >> 4, dd1 = e1 & 15; \
    hvl[cc1][dd1] = tmp[0][cc1][dd1]+tmp[1][cc1][dd1]+tmp[2][cc1][dd1]+tmp[3][cc1][dd1]; } \
  __syncthreads(); \
} while(0)

// ---------------- K2: routing, one q per block, 8 waves, 2 blocks/CU ----------------
__global__ __launch_bounds__(512, 2) void routing_kernel(const float* __restrict__ hat,
                                                         const float2* __restrict__ rs_g,
                                                         float* __restrict__ out)
{
  __shared__ float tmp[4][64][17];   // 17.4 KB
  __shared__ float hvl[64][17];      //  4.4 KB
  const int qidx = blockIdx.x;
  const int tid = threadIdx.x;
  const int w = tid >> 6;       // wave 0..7
  const int c = tid & 63;       // lane = capsule

  float qc[16];
  LD16(qc, hat + (size_t)(IN_CAPS + qidx)*CD + c*16);

  float qcc1[16];
  float s1, s2, s3;
  {
    float s=0.f;
    #pragma unroll
    for (int d=0;d<16;d++) s += qc[d];
    const float mean = s*(1.0f/16.0f);
    float n2=0.f;
    #pragma unroll
    for (int d=0;d<16;d++){ qcc1[d]=qc[d]-mean; n2 += qcc1[d]*qcc1[d]; }
    s1 = __frsqrt_rn(n2 + 1e-12f);
  }

  float v1[16], v2[16], acc[16];
  const int i0 = w*64, i1 = i0+64;

  // ======== pass 1:  hat_v1 = sum_i (1/64 + p1) * m ========
  #pragma unroll
  for (int d=0;d<16;d++) acc[d]=0.f;
  {
    const float* mp = hat + (size_t)i0*CD + c*16;
    const float2* rp = rs_g + i0*64 + c;
    for (int i=i0;i<i1;i+=2, mp+=2*CD, rp+=128){
      float ma[16], mb[16];
      LD16(ma, mp); LD16(mb, mp+CD);
      const float ra = rp[0].x, rb = rp[64].x;
      float nA, nB;
      DOT16(nA, ma, qcc1);
      DOT16(nB, mb, qcc1);
      const float wA = 0.015625f + tanh_fast(nA*ra*s1);
      const float wB = 0.015625f + tanh_fast(nB*rb*s1);
      #pragma unroll
      for (int d=0;d<16;d++){ acc[d] += wA*ma[d]; acc[d] += wB*mb[d]; }
    }
  }
  BLOCK_REDUCE();
  {
    float n2=0.f;
    #pragma unroll
    for (int d=0;d<16;d++){ v1[d]=hvl[c][d]; n2 += v1[d]*v1[d]; }
    const float sc = n2 / ((1.0f+n2)*sqrtf(n2+1e-8f));
    #pragma unroll
    for (int d=0;d<16;d++) v1[d] *= sc;
  }
  float mv1, mv2;
  {
    float sv=0.f;
    #pragma unroll
    for (int d=0;d<16;d++) sv += v1[d];
    mv1 = sv*(1.0f/16.0f);
    float s=0.f, ss=0.f;
    #pragma unroll
    for (int d=0;d<16;d++){ qc[d] = 0.5f*(qc[d]+v1[d]); s += qc[d]; ss += qc[d]*qc[d]; }
    const float mean = s*(1.0f/16.0f);
    s2 = __frsqrt_rn(ss - 16.0f*mean*mean + 1e-12f);
  }

  // ======== pass 2:  hat_v2 = sum_i (softmax_c(p1*cv1) + p2) * m ========
  #pragma unroll
  for (int d=0;d<16;d++) acc[d]=0.f;
  {
    const float* mp = hat + (size_t)i0*CD + c*16;
    const float2* rp = rs_g + i0*64 + c;
    for (int i=i0;i<i1;i+=2, mp+=2*CD, rp+=128){
      float ma[16], mb[16];
      LD16(ma, mp); LD16(mb, mp+CD);
      const float2 ra = rp[0], rb = rp[64];
      float n1A, cvA, n1B, cvB;
      DOT16(n1A, ma, qcc1); DOT16(cvA, ma, v1);
      DOT16(n1B, mb, qcc1); DOT16(cvB, mb, v1);
      const float p1A = tanh_fast(n1A*ra.x*s1);
      const float p2A = tanh_fast(0.5f*(n1A + cvA - mv1*ra.y)*ra.x*s2);
      const float p1B = tanh_fast(n1B*rb.x*s1);
      const float p2B = tanh_fast(0.5f*(n1B + cvB - mv1*rb.y)*rb.x*s2);
      const float eA = __expf(p1A*cvA);
      const float eB = __expf(p1B*cvB);
      const float sA = wave_sum64(eA);
      const float sB = wave_sum64(eB);
      const float wA = eA*__frcp_rn(sA) + p2A;
      const float wB = eB*__frcp_rn(sB) + p2B;
      #pragma unroll
      for (int d=0;d<16;d++){ acc[d] += wA*ma[d]; acc[d] += wB*mb[d]; }
    }
  }
  BLOCK_REDUCE();
  {
    float n2=0.f;
    #pragma unroll
    for (int d=0;d<16;d++){ v2[d]=hvl[c][d]; n2 += v2[d]*v2[d]; }
    const float sc = n2 / ((1.0f+n2)*sqrtf(n2+1e-8f));
    #pragma unroll
    for (int d=0;d<16;d++) v2[d] *= sc;
  }
  {
    float sv=0.f;
    #pragma unroll
    for (int d=0;d<16;d++) sv += v2[d];
    mv2 = sv*(1.0f/16.0f);
    float s=0.f, ss=0.f;
    #pragma unroll
    for (int d=0;d<16;d++){ qc[d] = 0.5f*(qc[d]+v2[d]); s += qc[d]; ss += qc[d]*qc[d]; }
    const float mean = s*(1.0f/16.0f);
    s3 = __frsqrt_rn(ss - 16.0f*mean*mean + 1e-12f);
  }

  // ======== pass 3:  out = squash( sum_i (softmax_c(p1*cv1+p2*cv2) + p3) * m ) ========
  #pragma unroll
  for (int d=0;d<16;d++) acc[d]=0.f;
  {
    const float* mp = hat + (size_t)i0*CD + c*16;
    const float2* rp = rs_g + i0*64 + c;
    for (int i=i0;i<i1;i+=2, mp+=2*CD, rp+=128){
      float ma[16], mb[16];
      LD16(ma, mp); LD16(mb, mp+CD);
      const float2 ra = rp[0], rb = rp[64];
      float n1A, cvA, cwA, n1B, cvB, cwB;
      DOT16(n1A, ma, qcc1); DOT16(cvA, ma, v1); DOT16(cwA, ma, v2);
      DOT16(n1B, mb, qcc1); DOT16(cvB, mb, v1); DOT16(cwB, mb, v2);
      const float p1A = tanh_fast(n1A*ra.x*s1);
      const float n2A = 0.5f*(n1A + cvA - mv1*ra.y);
      const float p2A = tanh_fast(n2A*ra.x*s2);
      const float p3A = tanh_fast(0.5f*(n2A + cwA - mv2*ra.y)*ra.x*s3);
      const float p1B = tanh_fast(n1B*rb.x*s1);
      const float n2B = 0.5f*(n1B + cvB - mv1*rb.y);
      const float p2B = tanh_fast(n2B*rb.x*s2);
      const float p3B = tanh_fast(0.5f*(n2B + cwB - mv2*rb.y)*rb.x*s3);
      const float eA = __expf(p1A*cvA + p2A*cwA);
      const float eB = __expf(p1B*cvB + p2B*cwB);
      const float sA = wave_sum64(eA);
      const float sB = wave_sum64(eB);
      const float wA = eA*__frcp_rn(sA) + p3A;
      const float wB = eB*__frcp_rn(sB) + p3B;
      #pragma unroll
      for (int d=0;d<16;d++){ acc[d] += wA*ma[d]; acc[d] += wB*mb[d]; }
    }
  }
  BLOCK_REDUCE();
  if (w==0){
    float hv[16]; float n2=0.f;
    #pragma unroll
    for (int d=0;d<16;d++){ hv[d]=hvl[c][d]; n2 += hv[d]*hv[d]; }
    const float sc = n2 / ((1.0f+n2)*sqrtf(n2+1e-8f));
    float4* op = (float4*)(out + (size_t)qidx*CD + c*16);
    float o[16];
    #pragma unroll
    for (int d=0;d<16;d++) o[d] = hv[d]*sc;
    op[0] = make_float4(o[0],o[1],o[2],o[3]);
    op[1] = make_float4(o[4],o[5],o[6],o[7]);
    op[2] = make_float4(o[8],o[9],o[10],o[11]);
    op[3] = make_float4(o[12],o[13],o[14],o[15]);
  }
}

extern "C" void kernel_launch(void* const* d_in, const int* in_sizes, int n_in,
                              void* d_out, int out_size, void* d_ws, size_t ws_size,
                              hipStream_t stream)
{
  const float* m  = (const float*)d_in[0];
  const float* q  = (const float*)d_in[1];
  const float* Ww = (const float*)d_in[2];
  const float* Wb = (const float*)d_in[3];
  float* out = (float*)d_out;

  float* hat  = (float*)d_ws;                 // 1024*1024 floats
  float2* rs  = (float2*)(hat + (size_t)1024*1024);   // 512*64 float2

  dim3 g0(16,16);
  gemm_hat<<<g0, 256, 0, stream>>>(m, q, Ww, Wb, hat);
  stats_kernel<<<128, 256, 0, stream>>>(hat, rs);
  routing_kernel<<<512, 512, 0, stream>>>(hat, rs, out);
}